// Round 9
// baseline (637.446 us; speedup 1.0000x reference)
//
#include <hip/hip_runtime.h>

// SVDQuantLinear: out[m,n] = x[m,:] . (w_q[n,:]*w_scale[n]) + bias[n] + lora
// Fold rank-32 LoRA into dequantized W (fp32, one bf16 round) -> one bf16 GEMM.
// R3: 256x256/BK=32 ring-4 counted-vmcnt -> 258-273us, MfmaUtil 46-48%.
// R4/R9/R10 FAILED: all phase-restructures (coarse 2ph, drain ring-2, faithful
//     fine 4-phase) land at 298-310us / 38-40%. R5 drain-removal 268us.
//     R6 fp32-A staging 366us. R8 reg-dbuf 261us (best gemm).
// R11 (this round): the one untested mechanism = INTER-BLOCK overlap.
//     All prior variants: one 8-wave block/CU (128KiB LDS) -> single barrier
//     group -> whole CU stalls at every gate (util == compute/(compute+gate)
//     == 46%). Now: R3-exact schedule at 128x128/BK=32 ring-4 -> 64KiB LDS
//     -> 2 independent blocks/CU (same 8 waves/CU). Block 0's gate overlaps
//     block 1's MFMA cluster (m114 mechanism; why the guide's 2-barrier
//     ladder peaked at 128^2). Staging/swizzle/gate-ladder bit-compatible
//     with refcheck-passed R3; only tile constants + wave mapping change.

#define M_DIM 8192   // B*S
#define N_DIM 4096   // D_OUT
#define K_DIM 4096   // D_IN
#define R_DIM 32

#define BM 128
#define BN 128
#define BK 32                 // 64 B per row in LDS
#define NT (K_DIM / BK)       // 128 k-tiles
#define NSLOT 4               // ring: 4 * (8KB A + 8KB B) = 64 KiB -> 2 blk/CU

typedef short bf16x8 __attribute__((ext_vector_type(8)));
typedef float f32x4 __attribute__((ext_vector_type(4)));
typedef unsigned short u16x8 __attribute__((ext_vector_type(8)));

#define GLOBAL_AS __attribute__((address_space(1)))
#define LDS_AS __attribute__((address_space(3)))

__device__ __forceinline__ unsigned short f2bf(float f) {
  union { float f; unsigned u; } v;
  v.f = f;
  unsigned u = v.u;
  u += 0x7fffu + ((u >> 16) & 1u);  // RNE (finite inputs)
  return (unsigned short)(u >> 16);
}

// ---------------- fused prep: cast x -> bf16 AND fold W_eff -> bf16 --------
#define CAST_BLOCKS 16384
__global__ void prep_kernel(const float* __restrict__ x,
                            const int* __restrict__ wq,
                            const float* __restrict__ wscale,
                            const float* __restrict__ lA,
                            const float* __restrict__ lS,
                            const float* __restrict__ lB,
                            unsigned short* __restrict__ Xbf,
                            unsigned short* __restrict__ Wbf) {
  __shared__ float bs[4][32];
  const int tid = threadIdx.x;

  if (blockIdx.x < CAST_BLOCKS) {
    size_t i = ((size_t)blockIdx.x * 256 + tid) * 8;
    float4 v0 = *(const float4*)(x + i);
    float4 v1 = *(const float4*)(x + i + 4);
    u16x8 o;
    o[0] = f2bf(v0.x); o[1] = f2bf(v0.y); o[2] = f2bf(v0.z); o[3] = f2bf(v0.w);
    o[4] = f2bf(v1.x); o[5] = f2bf(v1.y); o[6] = f2bf(v1.z); o[7] = f2bf(v1.w);
    *(u16x8*)(Xbf + i) = o;
    return;
  }

  const int bid2 = (int)blockIdx.x - CAST_BLOCKS;   // 0..2047
  const int o0 = (bid2 >> 1) * 4;                   // 1024 o-blocks x 4 rows
  const int i0 = (bid2 & 1) * 2048 + tid * 8;       // 2 i-blocks

  if (tid < 128) {
    int o = tid >> 5, r = tid & 31;
    bs[o][r] = lB[(size_t)(o0 + o) * R_DIM + r] * lS[r];
  }
  __syncthreads();

  float acc[4][8];
#pragma unroll
  for (int o = 0; o < 4; ++o)
#pragma unroll
    for (int j = 0; j < 8; ++j) acc[o][j] = 0.f;

  for (int r = 0; r < R_DIM; ++r) {
    float4 a0 = *(const float4*)(lA + (size_t)r * K_DIM + i0);
    float4 a1 = *(const float4*)(lA + (size_t)r * K_DIM + i0 + 4);
    float av[8] = {a0.x, a0.y, a0.z, a0.w, a1.x, a1.y, a1.z, a1.w};
#pragma unroll
    for (int o = 0; o < 4; ++o) {
      float b = bs[o][r];
#pragma unroll
      for (int j = 0; j < 8; ++j) acc[o][j] += b * av[j];
    }
  }

#pragma unroll
  for (int o = 0; o < 4; ++o) {
    float sc = wscale[o0 + o];
    const int* qp = wq + (size_t)(o0 + o) * K_DIM + i0;
    int4 q0 = *(const int4*)qp;
    int4 q1 = *(const int4*)(qp + 4);
    int qv[8] = {q0.x, q0.y, q0.z, q0.w, q1.x, q1.y, q1.z, q1.w};
    u16x8 ov;
#pragma unroll
    for (int j = 0; j < 8; ++j) ov[j] = f2bf(acc[o][j] + (float)qv[j] * sc);
    *(u16x8*)(Wbf + (size_t)(o0 + o) * K_DIM + i0) = ov;
  }
}

// ---------------- main GEMM: C = Xbf * Wbf^T + bias ------------------------
// 128x128 tile, BK=32, 256 thr = 4 waves (2M x 2N), wave = 64x64 output =
// 4x4 frags of 16x16x32 MFMA. 4-slot LDS ring (64 KiB total -> 2 blocks/CU);
// stage t+3 while computing t; counted vmcnt(8) gate once per K-tile.
// LDS: 16B line (row, sl) holds k-group g = sl ^ ((row>>1)&3); staging keeps
// LDS dest linear, permutes per-lane GLOBAL k-offset (rule #21; R3-proven).
__global__ __launch_bounds__(256, 2) void gemm_bias_kernel(
    const unsigned short* __restrict__ A,   // [M, K] bf16 bits
    const unsigned short* __restrict__ B,   // [N, K] bf16 bits
    const float* __restrict__ bias,         // [N]
    float* __restrict__ C) {                // [M, N]
  __shared__ __align__(16) unsigned short sA[NSLOT][BM * BK];  // 4 x 8 KiB
  __shared__ __align__(16) unsigned short sB[NSLOT][BN * BK];  // 4 x 8 KiB

  const int tid = threadIdx.x;
  const int lane = tid & 63;
  const int wv = tid >> 6;      // 0..3
  const int wm = wv >> 1;       // 0..1
  const int wn = wv & 1;        // 0..1

  // T1: bijective XCD swizzle (grid = 2048 = 8*256). XCD x owns 4 B-panels
  // (4 MB = its L2); A-panels stream via L3 (Xbf+Wbf = 96 MB fits L3).
  const int bid = (int)blockIdx.x;
  const int s = ((bid & 7) << 8) + (bid >> 3);
  const int bn_ = s >> 6;       // 0..31
  const int bm_ = s & 63;       // 0..63
  const size_t m0 = (size_t)bm_ * BM;
  const size_t n0 = (size_t)bn_ * BN;

  // ---- staging: lane l -> local row l>>2, 16B slot l&3,
  // global k-group (l&3)^((l>>3)&3); LDS dest linear (wave-uniform base).
  // Per operand per tile: 8 instrs block-wide = 4 waves x 2 (rows wv*32+0/16).
  const int lrow = lane >> 2;                                  // 0..15
  const int gsl = (((lane & 3) ^ ((lane >> 3) & 3))) * 8;      // k elems
  const int r0 = wv * 32 + lrow;                               // chunk c=0 row
  const unsigned short* gA0 = A + (m0 + r0) * (size_t)K_DIM + gsl;
  const unsigned short* gA1 = gA0 + 16 * (size_t)K_DIM;
  const unsigned short* gB0 = B + (n0 + r0) * (size_t)K_DIM + gsl;
  const unsigned short* gB1 = gB0 + 16 * (size_t)K_DIM;
  const int ch0 = (wv * 2 + 0) * 512;   // LDS chunk bases (shorts, 1KB each)
  const int ch1 = (wv * 2 + 1) * 512;

#define STAGE_ALL(kt, sl_)                                                    \
  do {                                                                        \
    const size_t ko = (size_t)(kt)*BK;                                        \
    __builtin_amdgcn_global_load_lds((const GLOBAL_AS void*)(gA0 + ko),       \
                                     (LDS_AS void*)(&sA[sl_][ch0]), 16, 0, 0);\
    __builtin_amdgcn_global_load_lds((const GLOBAL_AS void*)(gA1 + ko),       \
                                     (LDS_AS void*)(&sA[sl_][ch1]), 16, 0, 0);\
    __builtin_amdgcn_global_load_lds((const GLOBAL_AS void*)(gB0 + ko),       \
                                     (LDS_AS void*)(&sB[sl_][ch0]), 16, 0, 0);\
    __builtin_amdgcn_global_load_lds((const GLOBAL_AS void*)(gB1 + ko),       \
                                     (LDS_AS void*)(&sB[sl_][ch1]), 16, 0, 0);\
  } while (0)

  // ---- read addressing (16x16x32 frag: m = lane&15, k = (lane>>4)*8+j)
  const int rdrow = lane & 15;
  const int slot4 = (lane >> 4) ^ ((lane >> 1) & 3);           // swizzled slot
  const int aoff = (wm * 64 + rdrow) * BK + slot4 * 8;         // + mf*512
  const int boff = (wn * 64 + rdrow) * BK + slot4 * 8;         // + nf*512

  f32x4 acc[4][4];
#pragma unroll
  for (int mf = 0; mf < 4; ++mf)
#pragma unroll
    for (int nf = 0; nf < 4; ++nf) acc[mf][nf] = (f32x4){0.f, 0.f, 0.f, 0.f};

  // ---- prologue: 3 k-tiles in flight; wait only for tile 0 (vmcnt(8)).
  STAGE_ALL(0, 0);
  STAGE_ALL(1, 1);
  STAGE_ALL(2, 2);
  asm volatile("s_waitcnt vmcnt(8)" ::: "memory");
  __builtin_amdgcn_s_barrier();
  asm volatile("" ::: "memory");

  for (int t = 0; t < NT; ++t) {
    const int sl = t & 3;
    bf16x8 af[4], bfr[4];
#pragma unroll
    for (int mf = 0; mf < 4; ++mf)
      af[mf] = *(const bf16x8*)&sA[sl][aoff + mf * 512];
#pragma unroll
    for (int nf = 0; nf < 4; ++nf)
      bfr[nf] = *(const bf16x8*)&sB[sl][boff + nf * 512];

    if (t + 3 < NT) STAGE_ALL(t + 3, (t + 3) & 3);  // overwrites slot (t-1)&3

    // R3-proven: drain LDS reads, pin, tight MFMA cluster.
    asm volatile("s_waitcnt lgkmcnt(0)" ::: "memory");
    __builtin_amdgcn_sched_barrier(0);
    __builtin_amdgcn_s_setprio(1);
#pragma unroll
    for (int mf = 0; mf < 4; ++mf)
#pragma unroll
      for (int nf = 0; nf < 4; ++nf)
        acc[mf][nf] = __builtin_amdgcn_mfma_f32_16x16x32_bf16(
            af[mf], bfr[nf], acc[mf][nf], 0, 0, 0);
    __builtin_amdgcn_s_setprio(0);

    // gate: counted vmcnt keeps the 2 newest k-tiles (8 loads) in flight
    // across the barrier (T4, never a full drain in steady state).
    if (t < NT - 1) {
      if (t + 3 < NT) {
        asm volatile("s_waitcnt vmcnt(8)" ::: "memory");
      } else if (t + 3 == NT) {
        asm volatile("s_waitcnt vmcnt(4)" ::: "memory");
      } else {
        asm volatile("s_waitcnt vmcnt(0)" ::: "memory");
      }
      __builtin_amdgcn_s_barrier();
      asm volatile("" ::: "memory");
    }
  }
#undef STAGE_ALL

  // ---- epilogue: 16x16 C/D layout col = lane&15, row = (lane>>4)*4 + r
#pragma unroll
  for (int nf = 0; nf < 4; ++nf) {
    const int n = (int)n0 + wn * 64 + nf * 16 + (lane & 15);
    const float bv = bias[n];
#pragma unroll
    for (int mf = 0; mf < 4; ++mf) {
      const size_t mb = m0 + wm * 64 + mf * 16 + (lane >> 4) * 4;
#pragma unroll
      for (int r = 0; r < 4; ++r) {
        C[(mb + r) * N_DIM + n] = acc[mf][nf][r] + bv;
      }
    }
  }
}

// ---------------- fallback (only if ws too small) -------------------------
__global__ void fallback_kernel(const float* __restrict__ x,
                                const int* __restrict__ wq,
                                const float* __restrict__ wscale,
                                const float* __restrict__ bias,
                                float* __restrict__ out) {
  __shared__ float xs[K_DIM];
  const size_t m = blockIdx.x;
  for (int k = threadIdx.x; k < K_DIM; k += 256) xs[k] = x[m * K_DIM + k];
  __syncthreads();
  for (int n = threadIdx.x; n < N_DIM; n += 256) {
    const int* wr = wq + (size_t)n * K_DIM;
    float s = 0.f;
    for (int k = 0; k < K_DIM; ++k) s += xs[k] * (float)wr[k];
    out[m * N_DIM + n] = s * wscale[n] + bias[n];
  }
}

extern "C" void kernel_launch(void* const* d_in, const int* in_sizes, int n_in,
                              void* d_out, int out_size, void* d_ws, size_t ws_size,
                              hipStream_t stream) {
  const float* x       = (const float*)d_in[0];
  const int*   w_q     = (const int*)d_in[1];
  const float* w_scale = (const float*)d_in[2];
  const float* bias    = (const float*)d_in[3];
  const float* lora_A  = (const float*)d_in[4];
  const float* lora_S  = (const float*)d_in[5];
  const float* lora_B  = (const float*)d_in[6];
  float* out = (float*)d_out;

  const size_t need = ((size_t)M_DIM + N_DIM) * K_DIM * sizeof(unsigned short); // 96 MB
  if (ws_size < need) {
    fallback_kernel<<<M_DIM, 256, 0, stream>>>(x, w_q, w_scale, bias, out);
    return;
  }

  unsigned short* Xbf = (unsigned short*)d_ws;
  unsigned short* Wbf = Xbf + (size_t)M_DIM * K_DIM;

  prep_kernel<<<CAST_BLOCKS + (N_DIM / 4) * (K_DIM / 2048), 256, 0, stream>>>(
      x, w_q, w_scale, lora_A, lora_S, lora_B, Xbf, Wbf);
  gemm_bias_kernel<<<dim3((M_DIM / BM) * (N_DIM / BN)), 256, 0, stream>>>(
      Xbf, Wbf, bias, out);
}

// Round 10
// 547.155 us; speedup vs baseline: 1.1650x; 1.1650x over previous
//
#include <hip/hip_runtime.h>

// SVDQuantLinear: out[m,n] = x[m,:] . (w_q[n,:]*w_scale[n]) + bias[n] + lora
// Fold rank-32 LoRA into dequantized W (fp32, one bf16 round) -> one bf16 GEMM.
// R3: 256x256/BK=32 ring-4 counted-vmcnt -> 258-273us, MfmaUtil 46-48%.
// R4/R9/R10 FAILED: phase restructures 298-310us. R5 FAILED drain-removal.
// R6 FAILED fp32-A staging (FETCH 2x). R11 FAILED 128^2 2-blk/CU (FETCH 2x).
// R8 BEST: reg ping-pong dbuf on R3 schedule -> 261us.
// Constraint web mapped: 256^2 needed for FETCH 584MB -> 128KiB LDS ->
//     1 blk/CU -> phase-locked gates -> ~46% util ceiling for this family.
// R12 (this round): single bounded lever inside R8: MFMA 16x16x32 ->
//     32x32x16 (ubench 2382 vs 2075 TF; same FLOPs in 17% fewer matrix-pipe
//     cycles: 16 MFMA x 8.07cy = 129 vs 32 x 4.85 = 155 cy/wave/K-tile).
//     Reads unchanged (12 x ds_read_b128, same bytes); swizzle conflict-free
//     for 32-row frags (each 8-lane group covers all 32 banks once);
//     C/D layout col=lane&31, row=(reg&3)+8*(reg>>2)+4*(lane>>5) (m74/m101).
//     Watch dur not MfmaUtil (numerator shrinks -> util ~42% is expected).

#define M_DIM 8192   // B*S
#define N_DIM 4096   // D_OUT
#define K_DIM 4096   // D_IN
#define R_DIM 32

#define BM 256
#define BN 256
#define BK 32                 // 64 B per row in LDS
#define NT (K_DIM / BK)       // 128 k-tiles
#define NSLOT 4               // LDS ring: 4 * (16KB A + 16KB B) = 128 KiB

typedef short bf16x8 __attribute__((ext_vector_type(8)));
typedef float f32x16 __attribute__((ext_vector_type(16)));
typedef unsigned short u16x8 __attribute__((ext_vector_type(8)));

#define GLOBAL_AS __attribute__((address_space(1)))
#define LDS_AS __attribute__((address_space(3)))

__device__ __forceinline__ unsigned short f2bf(float f) {
  union { float f; unsigned u; } v;
  v.f = f;
  unsigned u = v.u;
  u += 0x7fffu + ((u >> 16) & 1u);  // RNE (finite inputs)
  return (unsigned short)(u >> 16);
}

// ---------------- fused prep: cast x -> bf16 AND fold W_eff -> bf16 --------
#define CAST_BLOCKS 16384
__global__ void prep_kernel(const float* __restrict__ x,
                            const int* __restrict__ wq,
                            const float* __restrict__ wscale,
                            const float* __restrict__ lA,
                            const float* __restrict__ lS,
                            const float* __restrict__ lB,
                            unsigned short* __restrict__ Xbf,
                            unsigned short* __restrict__ Wbf) {
  __shared__ float bs[4][32];
  const int tid = threadIdx.x;

  if (blockIdx.x < CAST_BLOCKS) {
    size_t i = ((size_t)blockIdx.x * 256 + tid) * 8;
    float4 v0 = *(const float4*)(x + i);
    float4 v1 = *(const float4*)(x + i + 4);
    u16x8 o;
    o[0] = f2bf(v0.x); o[1] = f2bf(v0.y); o[2] = f2bf(v0.z); o[3] = f2bf(v0.w);
    o[4] = f2bf(v1.x); o[5] = f2bf(v1.y); o[6] = f2bf(v1.z); o[7] = f2bf(v1.w);
    *(u16x8*)(Xbf + i) = o;
    return;
  }

  const int bid2 = (int)blockIdx.x - CAST_BLOCKS;   // 0..2047
  const int o0 = (bid2 >> 1) * 4;                   // 1024 o-blocks x 4 rows
  const int i0 = (bid2 & 1) * 2048 + tid * 8;       // 2 i-blocks

  if (tid < 128) {
    int o = tid >> 5, r = tid & 31;
    bs[o][r] = lB[(size_t)(o0 + o) * R_DIM + r] * lS[r];
  }
  __syncthreads();

  float acc[4][8];
#pragma unroll
  for (int o = 0; o < 4; ++o)
#pragma unroll
    for (int j = 0; j < 8; ++j) acc[o][j] = 0.f;

  for (int r = 0; r < R_DIM; ++r) {
    float4 a0 = *(const float4*)(lA + (size_t)r * K_DIM + i0);
    float4 a1 = *(const float4*)(lA + (size_t)r * K_DIM + i0 + 4);
    float av[8] = {a0.x, a0.y, a0.z, a0.w, a1.x, a1.y, a1.z, a1.w};
#pragma unroll
    for (int o = 0; o < 4; ++o) {
      float b = bs[o][r];
#pragma unroll
      for (int j = 0; j < 8; ++j) acc[o][j] += b * av[j];
    }
  }

#pragma unroll
  for (int o = 0; o < 4; ++o) {
    float sc = wscale[o0 + o];
    const int* qp = wq + (size_t)(o0 + o) * K_DIM + i0;
    int4 q0 = *(const int4*)qp;
    int4 q1 = *(const int4*)(qp + 4);
    int qv[8] = {q0.x, q0.y, q0.z, q0.w, q1.x, q1.y, q1.z, q1.w};
    u16x8 ov;
#pragma unroll
    for (int j = 0; j < 8; ++j) ov[j] = f2bf(acc[o][j] + (float)qv[j] * sc);
    *(u16x8*)(Wbf + (size_t)(o0 + o) * K_DIM + i0) = ov;
  }
}

// ---------------- main GEMM: C = Xbf * Wbf^T + bias ------------------------
// 256x256 tile, BK=32, 512 thr = 8 waves (2M x 4N), wave = 128x64 output =
// 4x2 tiles of 32x32, 2 k-steps of 16 -> 16 MFMA 32x32x16 per K-tile.
// Ring-4 LDS; R8 reg ping-pong; counted vmcnt gates (never full drain).
// LDS: 16B line (row, sl) holds k-group g = sl ^ ((row>>1)&3); staging keeps
// LDS dest linear, permutes per-lane GLOBAL k-offset (rule #21; R3-proven).
__global__ __launch_bounds__(512, 2) void gemm_bias_kernel(
    const unsigned short* __restrict__ A,   // [M, K] bf16 bits
    const unsigned short* __restrict__ B,   // [N, K] bf16 bits
    const float* __restrict__ bias,         // [N]
    float* __restrict__ C) {                // [M, N]
  __shared__ __align__(16) unsigned short sA[NSLOT][BM * BK];  // 4 x 16 KiB
  __shared__ __align__(16) unsigned short sB[NSLOT][BN * BK];  // 4 x 16 KiB

  const int tid = threadIdx.x;
  const int lane = tid & 63;
  const int wv = tid >> 6;      // 0..7
  const int wm = wv >> 2;       // 0..1
  const int wn = wv & 3;        // 0..3

  // T1: bijective XCD swizzle (grid = 512 = 8*64). XCD x owns 2 B-panels.
  const int bid = (int)blockIdx.x;
  const int s = ((bid & 7) << 6) + (bid >> 3);
  const int bn_ = s >> 5;       // 0..15
  const int bm_ = s & 31;       // 0..31
  const size_t m0 = (size_t)bm_ * BM;
  const size_t n0 = (size_t)bn_ * BN;

  // ---- staging: lane l -> local row l>>2, 16B slot l&3,
  // global k-group (l&3)^((l>>3)&3); LDS dest linear (wave-uniform base).
  const int lrow = lane >> 2;                                  // 0..15
  const int gsl = (((lane & 3) ^ ((lane >> 3) & 3))) * 8;      // k elems
  const int r0 = (wv * 2) * 16 + lrow;                         // chunk c=0 row
  const unsigned short* gA0 = A + (m0 + r0) * (size_t)K_DIM + gsl;
  const unsigned short* gA1 = gA0 + 16 * (size_t)K_DIM;
  const unsigned short* gB0 = B + (n0 + r0) * (size_t)K_DIM + gsl;
  const unsigned short* gB1 = gB0 + 16 * (size_t)K_DIM;
  const int ch0 = (wv * 2 + 0) * 512;   // LDS chunk bases (shorts, 1KB each)
  const int ch1 = (wv * 2 + 1) * 512;

#define STAGE_ALL(kt, sl_)                                                    \
  do {                                                                        \
    const size_t ko = (size_t)(kt)*BK;                                        \
    __builtin_amdgcn_global_load_lds((const GLOBAL_AS void*)(gA0 + ko),       \
                                     (LDS_AS void*)(&sA[sl_][ch0]), 16, 0, 0);\
    __builtin_amdgcn_global_load_lds((const GLOBAL_AS void*)(gA1 + ko),       \
                                     (LDS_AS void*)(&sA[sl_][ch1]), 16, 0, 0);\
    __builtin_amdgcn_global_load_lds((const GLOBAL_AS void*)(gB0 + ko),       \
                                     (LDS_AS void*)(&sB[sl_][ch0]), 16, 0, 0);\
    __builtin_amdgcn_global_load_lds((const GLOBAL_AS void*)(gB1 + ko),       \
                                     (LDS_AS void*)(&sB[sl_][ch1]), 16, 0, 0);\
  } while (0)

  // ---- read addressing (32x32x16 frag: m = lane&31, k = (lane>>5)*8 + j;
  // k-step ks -> 16B k-group g = ks*2 + (lane>>5); slot = g ^ ((row>>1)&3);
  // row = 32-aligned base + (lane&31) -> (row>>1)&3 == (lane>>1)&3).
  const int rdrow = lane & 31;
  const int rsw = (lane >> 1) & 3;
  const int kg = lane >> 5;                          // 0..1
  const int sl0 = ((0 * 2 + kg) ^ rsw) * 8;          // ks=0 slot (shorts)
  const int sl1 = ((1 * 2 + kg) ^ rsw) * 8;          // ks=1 slot
  const int ar = (wm * 128 + rdrow) * BK;            // + mt*32*BK
  const int br = (wn * 64 + rdrow) * BK;             // + nt*32*BK

  // AF index = mt*2+ks (mt 0..3); BF index = nt*2+ks (nt 0..1)
#define READ_FRAGS(AF, BF, sl_)                                               \
  do {                                                                        \
    _Pragma("unroll")                                                         \
    for (int nt = 0; nt < 2; ++nt) {                                          \
      BF[nt * 2 + 0] = *(const bf16x8*)&sB[sl_][br + nt * 1024 + sl0];        \
      BF[nt * 2 + 1] = *(const bf16x8*)&sB[sl_][br + nt * 1024 + sl1];        \
    }                                                                         \
    _Pragma("unroll")                                                         \
    for (int mt = 0; mt < 4; ++mt) {                                          \
      AF[mt * 2 + 0] = *(const bf16x8*)&sA[sl_][ar + mt * 1024 + sl0];        \
      AF[mt * 2 + 1] = *(const bf16x8*)&sA[sl_][ar + mt * 1024 + sl1];        \
    }                                                                         \
  } while (0)

#define MFMA_CLUSTER(AF, BF)                                                  \
  do {                                                                        \
    __builtin_amdgcn_s_setprio(1);                                            \
    _Pragma("unroll")                                                         \
    for (int ks = 0; ks < 2; ++ks)                                            \
      _Pragma("unroll")                                                       \
      for (int mt = 0; mt < 4; ++mt)                                          \
        _Pragma("unroll")                                                     \
        for (int nt = 0; nt < 2; ++nt)                                        \
          acc[mt][nt] = __builtin_amdgcn_mfma_f32_32x32x16_bf16(              \
              AF[mt * 2 + ks], BF[nt * 2 + ks], acc[mt][nt], 0, 0, 0);        \
    __builtin_amdgcn_s_setprio(0);                                            \
  } while (0)

#define GATE(cnt4)                                                            \
  do {                                                                        \
    asm volatile("s_waitcnt lgkmcnt(0)" ::: "memory");                        \
    if (cnt4) { asm volatile("s_waitcnt vmcnt(4)" ::: "memory"); }            \
    else      { asm volatile("s_waitcnt vmcnt(0)" ::: "memory"); }            \
    __builtin_amdgcn_s_barrier();                                             \
    asm volatile("" ::: "memory");                                            \
  } while (0)

  f32x16 acc[4][2];
#pragma unroll
  for (int mt = 0; mt < 4; ++mt)
#pragma unroll
    for (int nt = 0; nt < 2; ++nt)
#pragma unroll
      for (int r = 0; r < 16; ++r) acc[mt][nt][r] = 0.f;

  bf16x8 a0[8], b0[4], a1[8], b1[4];   // ping-pong fragment sets

  // ---- prologue: stage tiles 0-3; tiles 0,1 resident; read cur = tile 0.
  STAGE_ALL(0, 0);
  STAGE_ALL(1, 1);
  STAGE_ALL(2, 2);
  STAGE_ALL(3, 3);
  asm volatile("s_waitcnt vmcnt(8)" ::: "memory");
  __builtin_amdgcn_s_barrier();
  asm volatile("" ::: "memory");
  READ_FRAGS(a0, b0, 0);
  asm volatile("s_waitcnt lgkmcnt(0)" ::: "memory");
  __builtin_amdgcn_s_barrier();      // hard-separate cur-read from iter-0
  asm volatile("" ::: "memory");     // staging into slot 0

  for (int t = 0; t < NT; t += 2) {
    // ======== tile t: compute (a0,b0); prefetch tile t+1 -> (a1,b1) ========
    READ_FRAGS(a1, b1, (t + 1) & 3);
    if (t + 4 < NT) STAGE_ALL(t + 4, t & 3);
    __builtin_amdgcn_sched_barrier(0);
    MFMA_CLUSTER(a0, b0);
    GATE(t + 4 < NT);

    // ======== tile t+1: compute (a1,b1); prefetch tile t+2 -> (a0,b0) ======
    if (t + 2 < NT) READ_FRAGS(a0, b0, (t + 2) & 3);
    if (t + 5 < NT) STAGE_ALL(t + 5, (t + 1) & 3);
    __builtin_amdgcn_sched_barrier(0);
    MFMA_CLUSTER(a1, b1);
    if (t + 1 < NT - 1) GATE(t + 5 < NT);
  }
#undef STAGE_ALL
#undef READ_FRAGS
#undef MFMA_CLUSTER
#undef GATE

  // ---- epilogue: 32x32 C/D layout col = lane&31,
  // row = (r&3) + 8*(r>>2) + 4*(lane>>5)   (m74/m101-verified)
#pragma unroll
  for (int nt = 0; nt < 2; ++nt) {
    const int n = (int)n0 + wn * 64 + nt * 32 + (lane & 31);
    const float bv = bias[n];
#pragma unroll
    for (int mt = 0; mt < 4; ++mt) {
      const size_t mb = m0 + wm * 128 + mt * 32 + 4 * (lane >> 5);
#pragma unroll
      for (int r = 0; r < 16; ++r) {
        const size_t m = mb + (r & 3) + 8 * (r >> 2);
        C[m * N_DIM + n] = acc[mt][nt][r] + bv;
      }
    }
  }
}

// ---------------- fallback (only if ws too small) -------------------------
__global__ void fallback_kernel(const float* __restrict__ x,
                                const int* __restrict__ wq,
                                const float* __restrict__ wscale,
                                const float* __restrict__ bias,
                                float* __restrict__ out) {
  __shared__ float xs[K_DIM];
  const size_t m = blockIdx.x;
  for (int k = threadIdx.x; k < K_DIM; k += 256) xs[k] = x[m * K_DIM + k];
  __syncthreads();
  for (int n = threadIdx.x; n < N_DIM; n += 256) {
    const int* wr = wq + (size_t)n * K_DIM;
    float s = 0.f;
    for (int k = 0; k < K_DIM; ++k) s += xs[k] * (float)wr[k];
    out[m * N_DIM + n] = s * wscale[n] + bias[n];
  }
}

extern "C" void kernel_launch(void* const* d_in, const int* in_sizes, int n_in,
                              void* d_out, int out_size, void* d_ws, size_t ws_size,
                              hipStream_t stream) {
  const float* x       = (const float*)d_in[0];
  const int*   w_q     = (const int*)d_in[1];
  const float* w_scale = (const float*)d_in[2];
  const float* bias    = (const float*)d_in[3];
  const float* lora_A  = (const float*)d_in[4];
  const float* lora_S  = (const float*)d_in[5];
  const float* lora_B  = (const float*)d_in[6];
  float* out = (float*)d_out;

  const size_t need = ((size_t)M_DIM + N_DIM) * K_DIM * sizeof(unsigned short); // 96 MB
  if (ws_size < need) {
    fallback_kernel<<<M_DIM, 256, 0, stream>>>(x, w_q, w_scale, bias, out);
    return;
  }

  unsigned short* Xbf = (unsigned short*)d_ws;
  unsigned short* Wbf = Xbf + (size_t)M_DIM * K_DIM;

  prep_kernel<<<CAST_BLOCKS + (N_DIM / 4) * (K_DIM / 2048), 256, 0, stream>>>(
      x, w_q, w_scale, lora_A, lora_S, lora_B, Xbf, Wbf);
  gemm_bias_kernel<<<dim3((N_DIM / BN) * (M_DIM / BM)), 512, 0, stream>>>(
      Xbf, Wbf, bias, out);
}